// Round 15
// baseline (162.657 us; speedup 1.0000x reference)
//
#include <hip/hip_runtime.h>

#define S    4096
#define CH   256
#define NB   8

#define BM   128
#define BN   64
#define KSPLIT 8

#define SFF  256.0f     // F pre-scale (power of 2; argmax-invariant)
#define SLL  1024.0f    // L pre-scale

#define NEG_INF (-3.402823466e38f)

typedef _Float16 half8 __attribute__((ext_vector_type(8)));
typedef float    f32x4 __attribute__((ext_vector_type(4)));

// ---------------------------------------------------------------------------
// order-preserving compaction + inverse maps qpos/kpos
__global__ void compact(const int* __restrict__ flag, int* __restrict__ cnts,
                        int* __restrict__ qlist, int* __restrict__ klist,
                        int* __restrict__ qpos,  int* __restrict__ kpos) {
    __shared__ int sq[256], sk[256];
    int t = threadIdx.x;
    int base = t * 16;
    int f[16];
    int nq = 0, nk = 0;
    #pragma unroll
    for (int i = 0; i < 16; ++i) {
        f[i] = flag[base + i];
        nq += (f[i] == 1);
        nk += (f[i] == 0);
    }
    sq[t] = nq; sk[t] = nk;
    __syncthreads();
    for (int off = 1; off < 256; off <<= 1) {
        int vq = sq[t], vk = sk[t];
        int aq = (t >= off) ? sq[t - off] : 0;
        int ak = (t >= off) ? sk[t - off] : 0;
        __syncthreads();
        sq[t] = vq + aq; sk[t] = vk + ak;
        __syncthreads();
    }
    int pq = sq[t] - nq;
    int pk = sk[t] - nk;
    #pragma unroll
    for (int i = 0; i < 16; ++i) {
        if (f[i] == 1) { qpos[base + i] = pq; qlist[pq++] = base + i; }
        else           { kpos[base + i] = pk; klist[pk++] = base + i; }
    }
    if (t == 255) { cnts[0] = sq[255]; cnts[1] = sk[255]; }
}

// ---------------------------------------------------------------------------
// Fused transpose-pack.
//  y<4 : F strips (y*64 c) -> F2 fragment-ordered layout (coalesced preload).
//  y==4: L full-column two-pass: pass A = sumsq per k (ascending c), pass B =
//        scale+split+write.
// Panels per batch in out[:,0:512]: F2(4MB fragment-order) | LH | LL (row-major).
__global__ void pack_both(const float* __restrict__ x, const int* __restrict__ flag,
                          const int* __restrict__ qpos, const int* __restrict__ kpos,
                          float* __restrict__ out) {
    __shared__ float T[16][257];
    const int b = blockIdx.z;
    const int t = threadIdx.x;
    const int s = blockIdx.x * 256 + t;

    if (blockIdx.y < 4) {
        const int c0b = blockIdx.y * 64;
        const float* src = x + (size_t)b * 512 * S + blockIdx.x * 256;
        const bool active = (flag[s] == 1);
        const int row = active ? qpos[s] : 0;
        half8* F2 = (half8*)(out + (size_t)b * 768 * S);
        const int g  = row >> 4;
        const int sr = row & 15;
        for (int c0 = c0b; c0 < c0b + 64; c0 += 16) {
            #pragma unroll
            for (int i = 0; i < 16; ++i)
                T[i][t] = src[(size_t)(c0 + i) * S + t];
            __syncthreads();
            if (active) {
                #pragma unroll
                for (int g8 = 0; g8 < 2; ++g8) {
                    const int c  = c0 + g8 * 8;
                    const int cc = c >> 5;
                    const int l4 = (c >> 3) & 3;
                    half8 hb, lb;
                    #pragma unroll
                    for (int j = 0; j < 8; ++j) {
                        float v = T[g8 * 8 + j][t] * SFF;
                        _Float16 h = (_Float16)v;
                        hb[j] = h;
                        lb[j] = (_Float16)(v - (float)h);
                    }
                    F2[(size_t)(((g * 2 + 0) * 8 + cc) * 64) + sr * 4 + l4] = hb;
                    F2[(size_t)(((g * 2 + 1) * 8 + cc) * 64) + sr * 4 + l4] = lb;
                }
            }
            __syncthreads();
        }
    } else {
        const float* src = x + ((size_t)b * 512 + 256) * S + blockIdx.x * 256;
        const bool active = (flag[s] == 0);
        const int row = active ? kpos[s] : 0;
        _Float16* LH = (_Float16*)(out + (size_t)b * 768 * S) + 2 * (size_t)S * CH;
        _Float16* LL = LH + (size_t)S * CH;

        float acc = 0.f;
        for (int c0 = 0; c0 < CH; c0 += 16) {
            #pragma unroll
            for (int i = 0; i < 16; ++i)
                T[i][t] = src[(size_t)(c0 + i) * S + t];
            __syncthreads();
            #pragma unroll
            for (int i = 0; i < 16; ++i) {
                float v = T[i][t];
                acc += v * v;
            }
            __syncthreads();
        }
        const float w = active ? (1.0f / fmaxf(sqrtf(acc), 1e-12f)) * SLL : 0.f;

        for (int c0 = 0; c0 < CH; c0 += 16) {
            #pragma unroll
            for (int i = 0; i < 16; ++i)
                T[i][t] = src[(size_t)(c0 + i) * S + t];
            __syncthreads();
            if (active) {
                #pragma unroll
                for (int g8 = 0; g8 < 2; ++g8) {
                    union { _Float16 u[8]; float4 v; } hb, lb;
                    #pragma unroll
                    for (int j = 0; j < 8; ++j) {
                        float v = T[g8 * 8 + j][t] * w;
                        _Float16 h = (_Float16)v;
                        hb.u[j] = h;
                        lb.u[j] = (_Float16)(v - (float)h);
                    }
                    *(float4*)&LH[(size_t)row * CH + c0 + g8 * 8] = hb.v;
                    *(float4*)&LL[(size_t)row * CH + c0 + g8 * 8] = lb.v;
                }
            }
            __syncthreads();
        }
    }
}

// zero padding rows: F2 fragment-order for F, row-major for LH/LL
__global__ void zero_pad(const int* __restrict__ cnts, float* __restrict__ out) {
    const int b  = blockIdx.y;
    const int Aq = cnts[0], Ak = cnts[1];
    const int aqp = (Aq + BM - 1) & ~(BM - 1);
    const int akp = (Ak + BN - 1) & ~(BN - 1);
    _Float16* pb = (_Float16*)(out + (size_t)b * 768 * S);
    int i = blockIdx.x * 256 + threadIdx.x;
    half8 z = { 0, 0, 0, 0, 0, 0, 0, 0 };
    if (i < 8192) {                 // F2: 2 panels x (<=128 pad rows x 32 slots)
        int p = i >> 12, rem = i & 4095;
        int row = Aq + (rem >> 5);
        int sl  = rem & 31;
        if (row < aqp) {
            half8* F2 = (half8*)pb;
            F2[(size_t)((((row >> 4) * 2 + p) * 8 + (sl >> 2)) * 64) + (row & 15) * 4 + (sl & 3)] = z;
        }
    } else {                        // L panels: 2 x (64 rows x 32 half8)
        int j = i - 8192, panel = j >> 11, jdx = j & 2047;
        int row = Ak + (jdx >> 5);
        if (row < akp)
            *(half8*)(pb + (size_t)(2 + panel) * S * CH + (size_t)row * CH + (jdx & 31) * 8) = z;
    }
}

// ---------------------------------------------------------------------------
// MFMA argmax GEMM: 32 q-rows/wave (A panel 128 regs in AGPR via unified file),
// B via global_load_lds 6-buffer ring, 2 chunks/barrier phase, counted
// vmcnt(4), setprio. __launch_bounds__(256,2) pins 2 waves/SIMD (<=256 regs).
#define MFMA(A, B, C) __builtin_amdgcn_mfma_f32_16x16x32_f16((A), (B), (C), 0, 0, 0)

#define GLDS(SRC, OFF) __builtin_amdgcn_global_load_lds( \
    (const __attribute__((address_space(1))) void*)(SRC), \
    (__attribute__((address_space(3))) void*)(lds + (OFF)), 16, 0, 0)

#define STAGE(OFF) do { GLDS(s4, (OFF) + woff); GLDS(s5, (OFF) + 4096 + woff); } while (0)

#define ADV() do { \
    if (tn + 1 < nchunk) { \
        if ((tn & 7) == 7) { s4 += 32320; s5 += 32320; } \
        else               { s4 += 64;    s5 += 64;    } \
    } \
    ++tn; \
} while (0)

#define FOLD() do { \
    _Pragma("unroll") \
    for (int nt = 0; nt < 4; ++nt) { \
        int kp = kpb + nt * 16; \
        if (kp < Ak) { \
            _Pragma("unroll") \
            for (int mt = 0; mt < 2; ++mt) { \
                _Pragma("unroll") \
                for (int r = 0; r < 4; ++r) { \
                    const int ix = mt * 4 + r; \
                    float sv = acc[mt][nt][r]; \
                    if (sv > rm[ix]) { rm[ix] = sv; ri[ix] = kp; } \
                } \
            } \
        } \
        acc[0][nt] = (f32x4){0.f, 0.f, 0.f, 0.f}; \
        acc[1][nt] = (f32x4){0.f, 0.f, 0.f, 0.f}; \
    } \
    kpb += 64; \
} while (0)

// one 32-c chunk: 8 B-frag reads then 24 MFMAs.
// per-acc product order hh, hl, lh and ascending c — bitwise-same sims.
#define CBODY(BASE, CC) do { \
    const char* _bh = lds + (BASE) + boff0h; \
    const char* _bl = lds + (BASE) + boff0l; \
    half8 bh0 = *(const half8*)(_bh); \
    half8 bl0 = *(const half8*)(_bl); \
    half8 bh1 = *(const half8*)(_bh + 2048); \
    half8 bl1 = *(const half8*)(_bl + 2048); \
    half8 bh2 = *(const half8*)(_bh + 4096); \
    half8 bl2 = *(const half8*)(_bl + 4096); \
    half8 bh3 = *(const half8*)(_bh + 6144); \
    half8 bl3 = *(const half8*)(_bl + 6144); \
    acc[0][0] = MFMA(ah0[CC], bh0, acc[0][0]); \
    acc[1][0] = MFMA(ah1[CC], bh0, acc[1][0]); \
    acc[0][0] = MFMA(ah0[CC], bl0, acc[0][0]); \
    acc[1][0] = MFMA(ah1[CC], bl0, acc[1][0]); \
    acc[0][0] = MFMA(al0[CC], bh0, acc[0][0]); \
    acc[1][0] = MFMA(al1[CC], bh0, acc[1][0]); \
    acc[0][1] = MFMA(ah0[CC], bh1, acc[0][1]); \
    acc[1][1] = MFMA(ah1[CC], bh1, acc[1][1]); \
    acc[0][1] = MFMA(ah0[CC], bl1, acc[0][1]); \
    acc[1][1] = MFMA(ah1[CC], bl1, acc[1][1]); \
    acc[0][1] = MFMA(al0[CC], bh1, acc[0][1]); \
    acc[1][1] = MFMA(al1[CC], bh1, acc[1][1]); \
    acc[0][2] = MFMA(ah0[CC], bh2, acc[0][2]); \
    acc[1][2] = MFMA(ah1[CC], bh2, acc[1][2]); \
    acc[0][2] = MFMA(ah0[CC], bl2, acc[0][2]); \
    acc[1][2] = MFMA(ah1[CC], bl2, acc[1][2]); \
    acc[0][2] = MFMA(al0[CC], bh2, acc[0][2]); \
    acc[1][2] = MFMA(al1[CC], bh2, acc[1][2]); \
    acc[0][3] = MFMA(ah0[CC], bh3, acc[0][3]); \
    acc[1][3] = MFMA(ah1[CC], bh3, acc[1][3]); \
    acc[0][3] = MFMA(ah0[CC], bl3, acc[0][3]); \
    acc[1][3] = MFMA(ah1[CC], bl3, acc[1][3]); \
    acc[0][3] = MFMA(al0[CC], bh3, acc[0][3]); \
    acc[1][3] = MFMA(al1[CC], bh3, acc[1][3]); \
} while (0)

#define PHASE(J) do { \
    asm volatile("s_waitcnt vmcnt(4)" ::: "memory"); \
    __builtin_amdgcn_s_barrier(); \
    STAGE(sto); ADV(); \
    STAGE(sto + 8192); ADV(); \
    __builtin_amdgcn_s_setprio(1); \
    CBODY(rdo,        2 * (J)); \
    CBODY(rdo + 8192, 2 * (J) + 1); \
    __builtin_amdgcn_s_setprio(0); \
    rdo = (rdo == 32768) ? 0 : rdo + 16384; \
    sto = (sto == 32768) ? 0 : sto + 16384; \
} while (0)

__launch_bounds__(256, 2)
__global__ void argmax_mfma(const float* __restrict__ outbuf,
                            const int*  __restrict__ cnts,
                            float* __restrict__ pmax,
                            int*   __restrict__ pidx) {
    __shared__ __align__(1024) char lds[6 * 8192];   // 48 KB, 3 pair-slots

    const int Aq    = cnts[0];
    const int Ak    = cnts[1];
    const int b     = blockIdx.y;
    const int split = blockIdx.x & (KSPLIT - 1);
    const int q0    = (blockIdx.x >> 3) * BM;
    if (q0 >= Aq) return;

    const int tid  = threadIdx.x;
    const int lane = tid & 63;
    const int wid  = tid >> 6;      // wave owns q rows q0 + wid*32 .. +31
    const int l15  = lane & 15;
    const int l4   = lane >> 4;
    const int woff = wid * 1024;

    const _Float16* pb  = (const _Float16*)(outbuf + (size_t)b * 768 * S);
    const _Float16* LHg = pb + 2 * (size_t)S * CH;
    const _Float16* LLg = pb + 3 * (size_t)S * CH;

    const int nkt = (Ak + BN - 1) / BN;
    const int kt0 = (nkt * split) / KSPLIT;
    const int kt1 = (nkt * (split + 1)) / KSPLIT;
    const int nchunk = (kt1 - kt0) * 8;

    float rm[8]; int ri[8];
    #pragma unroll
    for (int i = 0; i < 8; ++i) { rm[i] = NEG_INF; ri[i] = 0; }

    // compressed B LDS read offsets (boff0l == boff0h ^ 64; nt adds 2048)
    const int boff0h = l15 * 128 + ((l4 * 16) ^ ((l15 & 7) << 4));
    const int boff0l = boff0h ^ 64;

    if (nchunk > 0) {
        // ---- A panel into registers: coalesced F2 fragment loads (32 x 1KB)
        half8 ah0[8], al0[8], ah1[8], al1[8];
        {
            const half8* F2 = (const half8*)pb;
            const int g0 = (q0 >> 4) + wid * 2;
            const int lo = l15 * 4 + l4;
            #pragma unroll
            for (int cc = 0; cc < 8; ++cc) {
                ah0[cc] = F2[(size_t)((((g0    ) * 2 + 0) * 8 + cc) * 64) + lo];
                al0[cc] = F2[(size_t)((((g0    ) * 2 + 1) * 8 + cc) * 64) + lo];
                ah1[cc] = F2[(size_t)((((g0 + 1) * 2 + 0) * 8 + cc) * 64) + lo];
                al1[cc] = F2[(size_t)((((g0 + 1) * 2 + 1) * 8 + cc) * 64) + lo];
            }
        }

        // ---- pre-swizzled global B source pointers (2 glds slots)
        const char *s4, *s5;
        {
            #define LSRC(P) ({ int s_ = (P) * 256 + tid; int row_ = s_ >> 3; \
                int ls_ = (s_ & 7) ^ (row_ & 7); \
                (const char*)(((ls_ < 4) ? LHg : LLg) + (size_t)(kt0 * BN + row_) * CH + (ls_ & 3) * 8); })
            s4 = LSRC(0); s5 = LSRC(1);
            #undef LSRC
        }
        int tn = 0;

        f32x4 acc[2][4];
        #pragma unroll
        for (int mt = 0; mt < 2; ++mt)
            #pragma unroll
            for (int nt = 0; nt < 4; ++nt) acc[mt][nt] = (f32x4){0.f, 0.f, 0.f, 0.f};

        int kpb = kt0 * BN + l15;

        STAGE(0);     ADV();
        STAGE(8192);  ADV();
        STAGE(16384); ADV();
        STAGE(24576); ADV();

        int rdo = 0;
        int sto = 32768;
        const int ngroup = kt1 - kt0;
        for (int g = 0; g < ngroup; ++g) {
            PHASE(0);
            PHASE(1);
            PHASE(2);
            PHASE(3);
            FOLD();
        }
    }

    // reduce across the 16 lanes sharing each q-row group
    #pragma unroll
    for (int mt = 0; mt < 2; ++mt) {
        #pragma unroll
        for (int r = 0; r < 4; ++r) {
            const int ix = mt * 4 + r;
            float m = rm[ix]; int id = ri[ix];
            #pragma unroll
            for (int off = 8; off; off >>= 1) {
                float om = __shfl_xor(m, off, 64);
                int   oi = __shfl_xor(id, off, 64);
                if (om > m || (om == m && oi < id)) { m = om; id = oi; }
            }
            if (l15 == 0) {
                int qp = q0 + wid * 32 + mt * 16 + l4 * 4 + r;
                if (qp < Aq) {
                    size_t o = ((size_t)((b << 12) + qp)) * KSPLIT + split;
                    pmax[o] = m;
                    pidx[o] = id;
                }
            }
        }
    }
}

// ---------------------------------------------------------------------------
// combine k-split partials (pidx holds COMPACT k index) -> idxb = klist[best]
__global__ void combine(const int* __restrict__ cnts, const int* __restrict__ qlist,
                        const int* __restrict__ klist,
                        const float* __restrict__ pmax, const int* __restrict__ pidx,
                        int* __restrict__ idxb) {
    int qp = blockIdx.x * 256 + threadIdx.x;
    int b  = blockIdx.y;
    if (qp >= cnts[0]) return;
    size_t base = (size_t)((b << 12) + qp) * KSPLIT;
    float m = pmax[base]; int id = pidx[base];
    #pragma unroll
    for (int s = 1; s < KSPLIT; ++s) {
        float om = pmax[base + s]; int oi = pidx[base + s];
        if (om > m) { m = om; id = oi; }   // lower split = smaller compact k
    }
    idxb[((size_t)b << 12) + qlist[qp]] = klist[id];
}

// ---------------------------------------------------------------------------
// fused writeback: out[:,0:512] = x (float4 copy); out[:,512:768] = shifted
__global__ void writeback(const float* __restrict__ x, const int* __restrict__ flag,
                          const int* __restrict__ idxb, float* __restrict__ out) {
    int i = blockIdx.x * 256 + threadIdx.x;   // float4 slot within [768][1024]
    int b = blockIdx.y;
    int c = i >> 10;
    float4* dst = (float4*)(out + (size_t)b * 768 * S) + i;
    if (c < 512) {
        *dst = ((const float4*)(x + (size_t)b * 512 * S))[i];
    } else {
        const float* src = x + ((size_t)b * 512 + 256 + (c - 512)) * S;
        const int* ib = idxb + ((size_t)b << 12);
        int q = (i & 1023) * 4;
        float4 v = { 0.f, 0.f, 0.f, 0.f };
        if (flag[q + 0] == 1) v.x = src[ib[q + 0]];
        if (flag[q + 1] == 1) v.y = src[ib[q + 1]];
        if (flag[q + 2] == 1) v.z = src[ib[q + 2]];
        if (flag[q + 3] == 1) v.w = src[ib[q + 3]];
        *dst = v;
    }
}

// ---------------------------------------------------------------------------
extern "C" void kernel_launch(void* const* d_in, const int* in_sizes, int n_in,
                              void* d_out, int out_size, void* d_ws, size_t ws_size,
                              hipStream_t stream) {
    const float* x    = (const float*)d_in[0];
    const int*   flag = (const int*)d_in[2];
    float*       out  = (float*)d_out;

    char* ws = (char*)d_ws;
    int*   cnts  = (int*)(ws);                 // 2 ints
    int*   qlist = (int*)(ws + 1024);          // 16 KB
    int*   klist = (int*)(ws + 17408);         // 16 KB
    int*   qpos  = (int*)(ws + 33792);         // 16 KB
    int*   kpos  = (int*)(ws + 50176);         // 16 KB
    int*   idxb  = (int*)(ws + 66560);         // 128 KB
    float* pmax  = (float*)(ws + 197632);      // 1 MB (8*4096*8)
    int*   pidx  = (int*)(ws + 1246208);       // 1 MB

    hipLaunchKernelGGL(compact,     dim3(1),                     dim3(256), 0, stream, flag, cnts, qlist, klist, qpos, kpos);
    hipLaunchKernelGGL(pack_both,   dim3(S / 256, 5, NB),        dim3(256), 0, stream, x, flag, qpos, kpos, out);
    hipLaunchKernelGGL(zero_pad,    dim3(48, NB),                dim3(256), 0, stream, cnts, out);
    hipLaunchKernelGGL(argmax_mfma, dim3((S / BM) * KSPLIT, NB), dim3(256), 0, stream, out, cnts, pmax, pidx);
    hipLaunchKernelGGL(combine,     dim3(S / 256, NB),           dim3(256), 0, stream, cnts, qlist, klist, pmax, pidx, idxb);
    hipLaunchKernelGGL(writeback,   dim3(768 * 1024 / 256, NB),  dim3(256), 0, stream, x, flag, idxb, out);
}

// Round 16
// 158.061 us; speedup vs baseline: 1.0291x; 1.0291x over previous
//
#include <hip/hip_runtime.h>

#define S    4096
#define CH   256
#define NB   8

#define BM   64
#define BN   64
#define KSPLIT 8

#define SFF  256.0f     // F pre-scale (power of 2; argmax-invariant)
#define SLL  1024.0f    // L pre-scale

#define NEG_INF (-3.402823466e38f)

typedef _Float16 half8 __attribute__((ext_vector_type(8)));
typedef float    f32x4 __attribute__((ext_vector_type(4)));

// ---------------------------------------------------------------------------
// order-preserving compaction + inverse maps qpos/kpos
__global__ void compact(const int* __restrict__ flag, int* __restrict__ cnts,
                        int* __restrict__ qlist, int* __restrict__ klist,
                        int* __restrict__ qpos,  int* __restrict__ kpos) {
    __shared__ int sq[256], sk[256];
    int t = threadIdx.x;
    int base = t * 16;
    int f[16];
    int nq = 0, nk = 0;
    #pragma unroll
    for (int i = 0; i < 16; ++i) {
        f[i] = flag[base + i];
        nq += (f[i] == 1);
        nk += (f[i] == 0);
    }
    sq[t] = nq; sk[t] = nk;
    __syncthreads();
    for (int off = 1; off < 256; off <<= 1) {
        int vq = sq[t], vk = sk[t];
        int aq = (t >= off) ? sq[t - off] : 0;
        int ak = (t >= off) ? sk[t - off] : 0;
        __syncthreads();
        sq[t] = vq + aq; sk[t] = vk + ak;
        __syncthreads();
    }
    int pq = sq[t] - nq;
    int pk = sk[t] - nk;
    #pragma unroll
    for (int i = 0; i < 16; ++i) {
        if (f[i] == 1) { qpos[base + i] = pq; qlist[pq++] = base + i; }
        else           { kpos[base + i] = pk; klist[pk++] = base + i; }
    }
    if (t == 255) { cnts[0] = sq[255]; cnts[1] = sk[255]; }
}

// ---------------------------------------------------------------------------
// Fused transpose-pack.
//  y<4 : F strips (y*64 c) -> F2 fragment-ordered layout (coalesced preload).
//  y==4: L full-column two-pass: pass A = sumsq per k (ascending c), pass B =
//        scale+split+write.
// Panels per batch in out[:,0:512]: F2(4MB fragment-order) | LH | LL (row-major).
__global__ void pack_both(const float* __restrict__ x, const int* __restrict__ flag,
                          const int* __restrict__ qpos, const int* __restrict__ kpos,
                          float* __restrict__ out) {
    __shared__ float T[16][257];
    const int b = blockIdx.z;
    const int t = threadIdx.x;
    const int s = blockIdx.x * 256 + t;

    if (blockIdx.y < 4) {
        const int c0b = blockIdx.y * 64;
        const float* src = x + (size_t)b * 512 * S + blockIdx.x * 256;
        const bool active = (flag[s] == 1);
        const int row = active ? qpos[s] : 0;
        half8* F2 = (half8*)(out + (size_t)b * 768 * S);
        const int g  = row >> 4;
        const int sr = row & 15;
        for (int c0 = c0b; c0 < c0b + 64; c0 += 16) {
            #pragma unroll
            for (int i = 0; i < 16; ++i)
                T[i][t] = src[(size_t)(c0 + i) * S + t];
            __syncthreads();
            if (active) {
                #pragma unroll
                for (int g8 = 0; g8 < 2; ++g8) {
                    const int c  = c0 + g8 * 8;
                    const int cc = c >> 5;
                    const int l4 = (c >> 3) & 3;
                    half8 hb, lb;
                    #pragma unroll
                    for (int j = 0; j < 8; ++j) {
                        float v = T[g8 * 8 + j][t] * SFF;
                        _Float16 h = (_Float16)v;
                        hb[j] = h;
                        lb[j] = (_Float16)(v - (float)h);
                    }
                    F2[(size_t)(((g * 2 + 0) * 8 + cc) * 64) + sr * 4 + l4] = hb;
                    F2[(size_t)(((g * 2 + 1) * 8 + cc) * 64) + sr * 4 + l4] = lb;
                }
            }
            __syncthreads();
        }
    } else {
        const float* src = x + ((size_t)b * 512 + 256) * S + blockIdx.x * 256;
        const bool active = (flag[s] == 0);
        const int row = active ? kpos[s] : 0;
        _Float16* LH = (_Float16*)(out + (size_t)b * 768 * S) + 2 * (size_t)S * CH;
        _Float16* LL = LH + (size_t)S * CH;

        float acc = 0.f;
        for (int c0 = 0; c0 < CH; c0 += 16) {
            #pragma unroll
            for (int i = 0; i < 16; ++i)
                T[i][t] = src[(size_t)(c0 + i) * S + t];
            __syncthreads();
            #pragma unroll
            for (int i = 0; i < 16; ++i) {
                float v = T[i][t];
                acc += v * v;
            }
            __syncthreads();
        }
        const float w = active ? (1.0f / fmaxf(sqrtf(acc), 1e-12f)) * SLL : 0.f;

        for (int c0 = 0; c0 < CH; c0 += 16) {
            #pragma unroll
            for (int i = 0; i < 16; ++i)
                T[i][t] = src[(size_t)(c0 + i) * S + t];
            __syncthreads();
            if (active) {
                #pragma unroll
                for (int g8 = 0; g8 < 2; ++g8) {
                    union { _Float16 u[8]; float4 v; } hb, lb;
                    #pragma unroll
                    for (int j = 0; j < 8; ++j) {
                        float v = T[g8 * 8 + j][t] * w;
                        _Float16 h = (_Float16)v;
                        hb.u[j] = h;
                        lb.u[j] = (_Float16)(v - (float)h);
                    }
                    *(float4*)&LH[(size_t)row * CH + c0 + g8 * 8] = hb.v;
                    *(float4*)&LL[(size_t)row * CH + c0 + g8 * 8] = lb.v;
                }
            }
            __syncthreads();
        }
    }
}

// zero padding rows: F2 fragment-order for F, row-major for LH/LL
__global__ void zero_pad(const int* __restrict__ cnts, float* __restrict__ out) {
    const int b  = blockIdx.y;
    const int Aq = cnts[0], Ak = cnts[1];
    const int aqp = (Aq + BM - 1) & ~(BM - 1);
    const int akp = (Ak + BN - 1) & ~(BN - 1);
    _Float16* pb = (_Float16*)(out + (size_t)b * 768 * S);
    int i = blockIdx.x * 256 + threadIdx.x;
    half8 z = { 0, 0, 0, 0, 0, 0, 0, 0 };
    if (i < 8192) {                 // F2: 2 panels x (<=128 pad rows x 32 slots)
        int p = i >> 12, rem = i & 4095;
        int row = Aq + (rem >> 5);
        int sl  = rem & 31;
        if (row < aqp) {
            half8* F2 = (half8*)pb;
            F2[(size_t)((((row >> 4) * 2 + p) * 8 + (sl >> 2)) * 64) + (row & 15) * 4 + (sl & 3)] = z;
        }
    } else {                        // L panels: 2 x (64 rows x 32 half8)
        int j = i - 8192, panel = j >> 11, jdx = j & 2047;
        int row = Ak + (jdx >> 5);
        if (row < akp)
            *(half8*)(pb + (size_t)(2 + panel) * S * CH + (size_t)row * CH + (jdx & 31) * 8) = z;
    }
}

// ---------------------------------------------------------------------------
// MFMA argmax GEMM: light waves (16 q-rows each, A panel 64 regs), B via
// global_load_lds 4-buffer single-chunk ring (32 KB), counted vmcnt(4),
// setprio. KSPLIT=8. Ring shrunk from 48KB for +2 blocks/CU residency.
#define MFMA(A, B, C) __builtin_amdgcn_mfma_f32_16x16x32_f16((A), (B), (C), 0, 0, 0)

#define GLDS(SRC, OFF) __builtin_amdgcn_global_load_lds( \
    (const __attribute__((address_space(1))) void*)(SRC), \
    (__attribute__((address_space(3))) void*)(lds + (OFF)), 16, 0, 0)

#define STAGE(OFF) do { GLDS(s4, (OFF) + woff); GLDS(s5, (OFF) + 4096 + woff); } while (0)

#define ADV() do { \
    if (tn + 1 < nchunk) { \
        if ((tn & 7) == 7) { s4 += 32320; s5 += 32320; } \
        else               { s4 += 64;    s5 += 64;    } \
    } \
    ++tn; \
} while (0)

#define FOLD() do { \
    _Pragma("unroll") \
    for (int nt = 0; nt < 4; ++nt) { \
        int kp = kpb + nt * 16; \
        if (kp < Ak) { \
            _Pragma("unroll") \
            for (int r = 0; r < 4; ++r) { \
                float sv = acc[nt][r]; \
                if (sv > rm[r]) { rm[r] = sv; ri[r] = kp; } \
            } \
        } \
        acc[nt] = (f32x4){0.f, 0.f, 0.f, 0.f}; \
    } \
    kpb += 64; \
} while (0)

// one 32-c chunk; per-acc product order hh, hl, lh (bitwise-same as R8..R14)
#define CBODY(BASE, CC) do { \
    const char* _bh = lds + (BASE) + boff0h; \
    const char* _bl = lds + (BASE) + boff0l; \
    half8 bh0 = *(const half8*)(_bh); \
    half8 bl0 = *(const half8*)(_bl); \
    half8 bh1 = *(const half8*)(_bh + 2048); \
    half8 bl1 = *(const half8*)(_bl + 2048); \
    half8 bh2 = *(const half8*)(_bh + 4096); \
    half8 bl2 = *(const half8*)(_bl + 4096); \
    half8 bh3 = *(const half8*)(_bh + 6144); \
    half8 bl3 = *(const half8*)(_bl + 6144); \
    acc[0] = MFMA(ah[CC], bh0, acc[0]); \
    acc[1] = MFMA(ah[CC], bh1, acc[1]); \
    acc[2] = MFMA(ah[CC], bh2, acc[2]); \
    acc[3] = MFMA(ah[CC], bh3, acc[3]); \
    acc[0] = MFMA(ah[CC], bl0, acc[0]); \
    acc[1] = MFMA(ah[CC], bl1, acc[1]); \
    acc[2] = MFMA(ah[CC], bl2, acc[2]); \
    acc[3] = MFMA(ah[CC], bl3, acc[3]); \
    acc[0] = MFMA(al[CC], bh0, acc[0]); \
    acc[1] = MFMA(al[CC], bh1, acc[1]); \
    acc[2] = MFMA(al[CC], bh2, acc[2]); \
    acc[3] = MFMA(al[CC], bh3, acc[3]); \
} while (0)

// one phase = one chunk; buffer = slot (t&3), stage target = slot (t+3)&3
#define ITER(TL, BUFL, NXL) do { \
    asm volatile("s_waitcnt vmcnt(4)" ::: "memory"); \
    __builtin_amdgcn_s_barrier(); \
    STAGE(NXL); ADV(); \
    __builtin_amdgcn_s_setprio(1); \
    CBODY(BUFL, TL); \
    __builtin_amdgcn_s_setprio(0); \
    if (((TL) & 7) == 7) FOLD(); \
} while (0)

__launch_bounds__(256)
__global__ void argmax_mfma(const float* __restrict__ outbuf,
                            const int*  __restrict__ cnts,
                            float* __restrict__ pmax,
                            int*   __restrict__ pidx) {
    __shared__ __align__(1024) char lds[4 * 8192];   // 32 KB, 4 single-chunk slots

    const int Aq    = cnts[0];
    const int Ak    = cnts[1];
    const int b     = blockIdx.y;
    const int split = blockIdx.x & (KSPLIT - 1);
    const int q0    = (blockIdx.x >> 3) * BM;
    if (q0 >= Aq) return;

    const int tid  = threadIdx.x;
    const int lane = tid & 63;
    const int wid  = tid >> 6;      // wave owns q rows q0 + wid*16 .. +15
    const int l15  = lane & 15;
    const int l4   = lane >> 4;
    const int woff = wid * 1024;

    const _Float16* pb  = (const _Float16*)(outbuf + (size_t)b * 768 * S);
    const _Float16* LHg = pb + 2 * (size_t)S * CH;
    const _Float16* LLg = pb + 3 * (size_t)S * CH;

    const int nkt = (Ak + BN - 1) / BN;
    const int kt0 = (nkt * split) / KSPLIT;
    const int kt1 = (nkt * (split + 1)) / KSPLIT;
    const int nchunk = (kt1 - kt0) * 8;

    float rm[4]; int ri[4];
    #pragma unroll
    for (int i = 0; i < 4; ++i) { rm[i] = NEG_INF; ri[i] = 0; }

    // compressed B LDS read offsets: boff0l == boff0h ^ 64; nt adds 2048
    const int boff0h = l15 * 128 + ((l4 * 16) ^ ((l15 & 7) << 4));
    const int boff0l = boff0h ^ 64;

    if (nchunk > 0) {
        // ---- A panel into registers: coalesced F2 fragment loads (16 x 1KB)
        half8 ah[8], al[8];
        {
            const half8* F2 = (const half8*)pb;
            const int g0 = (q0 >> 4) + wid;
            const int lo = l15 * 4 + l4;
            #pragma unroll
            for (int cc = 0; cc < 8; ++cc) {
                ah[cc] = F2[(size_t)(((g0 * 2 + 0) * 8 + cc) * 64) + lo];
                al[cc] = F2[(size_t)(((g0 * 2 + 1) * 8 + cc) * 64) + lo];
            }
        }

        // ---- pre-swizzled global B source pointers (2 glds slots)
        const char *s4, *s5;
        {
            #define LSRC(P) ({ int s_ = (P) * 256 + tid; int row_ = s_ >> 3; \
                int ls_ = (s_ & 7) ^ (row_ & 7); \
                (const char*)(((ls_ < 4) ? LHg : LLg) + (size_t)(kt0 * BN + row_) * CH + (ls_ & 3) * 8); })
            s4 = LSRC(0); s5 = LSRC(1);
            #undef LSRC
        }
        int tn = 0;

        f32x4 acc[4];
        #pragma unroll
        for (int nt = 0; nt < 4; ++nt) acc[nt] = (f32x4){0.f, 0.f, 0.f, 0.f};

        int kpb = kt0 * BN + l15;

        // prologue: stage chunks 0,1,2 into slots 0,1,2 (6 glds outstanding)
        STAGE(0);     ADV();
        STAGE(8192);  ADV();
        STAGE(16384); ADV();

        for (int t = 0; t < nchunk; t += 8) {
            ITER(0, 0,     24576);
            ITER(1, 8192,  0);
            ITER(2, 16384, 8192);
            ITER(3, 24576, 16384);
            ITER(4, 0,     24576);
            ITER(5, 8192,  0);
            ITER(6, 16384, 8192);
            ITER(7, 24576, 16384);
        }
    }

    // reduce across the 16 lanes sharing each q-row group
    #pragma unroll
    for (int r = 0; r < 4; ++r) {
        float m = rm[r]; int id = ri[r];
        #pragma unroll
        for (int off = 8; off; off >>= 1) {
            float om = __shfl_xor(m, off, 64);
            int   oi = __shfl_xor(id, off, 64);
            if (om > m || (om == m && oi < id)) { m = om; id = oi; }
        }
        if (l15 == 0) {
            int qp = q0 + wid * 16 + l4 * 4 + r;
            if (qp < Aq) {
                size_t o = ((size_t)((b << 12) + qp)) * KSPLIT + split;
                pmax[o] = m;
                pidx[o] = id;
            }
        }
    }
}

// ---------------------------------------------------------------------------
// combine k-split partials (pidx holds COMPACT k index) -> idxb = klist[best]
__global__ void combine(const int* __restrict__ cnts, const int* __restrict__ qlist,
                        const int* __restrict__ klist,
                        const float* __restrict__ pmax, const int* __restrict__ pidx,
                        int* __restrict__ idxb) {
    int qp = blockIdx.x * 256 + threadIdx.x;
    int b  = blockIdx.y;
    if (qp >= cnts[0]) return;
    size_t base = (size_t)((b << 12) + qp) * KSPLIT;
    float m = pmax[base]; int id = pidx[base];
    #pragma unroll
    for (int s = 1; s < KSPLIT; ++s) {
        float om = pmax[base + s]; int oi = pidx[base + s];
        if (om > m) { m = om; id = oi; }   // lower split = smaller compact k
    }
    idxb[((size_t)b << 12) + qlist[qp]] = klist[id];
}

// ---------------------------------------------------------------------------
// fused writeback: out[:,0:512] = x (float4 copy); out[:,512:768] = shifted
__global__ void writeback(const float* __restrict__ x, const int* __restrict__ flag,
                          const int* __restrict__ idxb, float* __restrict__ out) {
    int i = blockIdx.x * 256 + threadIdx.x;   // float4 slot within [768][1024]
    int b = blockIdx.y;
    int c = i >> 10;
    float4* dst = (float4*)(out + (size_t)b * 768 * S) + i;
    if (c < 512) {
        *dst = ((const float4*)(x + (size_t)b * 512 * S))[i];
    } else {
        const float* src = x + ((size_t)b * 512 + 256 + (c - 512)) * S;
        const int* ib = idxb + ((size_t)b << 12);
        int q = (i & 1023) * 4;
        float4 v = { 0.f, 0.f, 0.f, 0.f };
        if (flag[q + 0] == 1) v.x = src[ib[q + 0]];
        if (flag[q + 1] == 1) v.y = src[ib[q + 1]];
        if (flag[q + 2] == 1) v.z = src[ib[q + 2]];
        if (flag[q + 3] == 1) v.w = src[ib[q + 3]];
        *dst = v;
    }
}

// ---------------------------------------------------------------------------
extern "C" void kernel_launch(void* const* d_in, const int* in_sizes, int n_in,
                              void* d_out, int out_size, void* d_ws, size_t ws_size,
                              hipStream_t stream) {
    const float* x    = (const float*)d_in[0];
    const int*   flag = (const int*)d_in[2];
    float*       out  = (float*)d_out;

    char* ws = (char*)d_ws;
    int*   cnts  = (int*)(ws);                 // 2 ints
    int*   qlist = (int*)(ws + 1024);          // 16 KB
    int*   klist = (int*)(ws + 17408);         // 16 KB
    int*   qpos  = (int*)(ws + 33792);         // 16 KB
    int*   kpos  = (int*)(ws + 50176);         // 16 KB
    int*   idxb  = (int*)(ws + 66560);         // 128 KB
    float* pmax  = (float*)(ws + 197632);      // 1 MB (8*4096*8)
    int*   pidx  = (int*)(ws + 1246208);       // 1 MB

    hipLaunchKernelGGL(compact,     dim3(1),                     dim3(256), 0, stream, flag, cnts, qlist, klist, qpos, kpos);
    hipLaunchKernelGGL(pack_both,   dim3(S / 256, 5, NB),        dim3(256), 0, stream, x, flag, qpos, kpos, out);
    hipLaunchKernelGGL(zero_pad,    dim3(48, NB),                dim3(256), 0, stream, cnts, out);
    hipLaunchKernelGGL(argmax_mfma, dim3((S / BM) * KSPLIT, NB), dim3(256), 0, stream, out, cnts, pmax, pidx);
    hipLaunchKernelGGL(combine,     dim3(S / 256, NB),           dim3(256), 0, stream, cnts, qlist, klist, pmax, pidx, idxb);
    hipLaunchKernelGGL(writeback,   dim3(768 * 1024 / 256, NB),  dim3(256), 0, stream, x, flag, idxb, out);
}